// Round 1
// baseline (245.710 us; speedup 1.0000x reference)
//
#include <hip/hip_runtime.h>
#include <hip/hip_bf16.h>

typedef __attribute__((ext_vector_type(8))) short bf16x8;
typedef __attribute__((ext_vector_type(4))) float f32x4;
typedef __attribute__((ext_vector_type(4))) float f4v;
typedef __attribute__((ext_vector_type(4))) short s4v;

__device__ __forceinline__ short f2bf(float f) {
    union { __hip_bfloat16 h; short s; } u;
    u.h = __float2bfloat16(f);
    return u.s;
}

__device__ __forceinline__ void gload_lds16(const void* g, void* l) {
    __builtin_amdgcn_global_load_lds(
        (const __attribute__((address_space(1))) void*)g,
        (__attribute__((address_space(3))) void*)l,
        16, 0, 0);
}

// ---------------- f32 -> bf16 conversion ----------------
__global__ void cvt_kernel(const float* __restrict__ in,
                           __hip_bfloat16* __restrict__ out, int n4) {
    int i = blockIdx.x * blockDim.x + threadIdx.x;
    int stride = gridDim.x * blockDim.x;
    for (; i < n4; i += stride) {
        f4v v = ((const f4v*)in)[i];
        s4v o;
        #pragma unroll
        for (int j = 0; j < 4; ++j) o[j] = f2bf(v[j]);
        ((s4v*)out)[i] = o;
    }
}

// ---------------- per-batch scale ----------------
__global__ void scale_kernel(const float* __restrict__ pd,
                             const float* __restrict__ alphap,
                             float* __restrict__ scales) {
    int b = blockIdx.x;
    float s = 0.f;
    for (int i = threadIdx.x; i < 2048; i += 256) s += pd[b * 2048 + i];
    for (int o = 32; o; o >>= 1) s += __shfl_down(s, o);
    __shared__ float wsum[4];
    if ((threadIdx.x & 63) == 0) wsum[threadIdx.x >> 6] = s;
    __syncthreads();
    if (threadIdx.x == 0) {
        float t = wsum[0] + wsum[1] + wsum[2] + wsum[3];
        float mean = t * (1.0f / 2048.0f);
        float temp = fmaxf(1.0f + alphap[0] * mean, 1e-6f);
        scales[b] = 0.125f * temp;   // SCALE = 64^-0.5
    }
}

// ---------------- NT GEMM: C[M,N] = A[M,K] * B[N,K]^T + bias ----------------
// 128x128 tile, BK=64, 256 threads (4 waves, 2x2), swizzled LDS staging.
template<int BF16_OUT>
__global__ __launch_bounds__(256, 2)
void gemm_nt(const __hip_bfloat16* __restrict__ A,
             const __hip_bfloat16* __restrict__ Bw,
             const float* __restrict__ bias,
             void* __restrict__ Cv,
             int M, int N, int K) {
    __shared__ short sA[128 * 64];
    __shared__ short sB[128 * 64];
    const int tid = threadIdx.x;
    const int wave = tid >> 6, lane = tid & 63;
    const int g = lane >> 4, c = lane & 15;
    const int wr = wave >> 1, wc = wave & 1;
    const long m0 = (long)blockIdx.y * 128, n0 = (long)blockIdx.x * 128;

    f32x4 acc[4][4];
    #pragma unroll
    for (int m = 0; m < 4; ++m)
        #pragma unroll
        for (int n = 0; n < 4; ++n) acc[m][n] = f32x4{0.f, 0.f, 0.f, 0.f};

    for (int k0 = 0; k0 < K; k0 += 64) {
        #pragma unroll
        for (int i = 0; i < 4; ++i) {
            int cb = (i * 4 + wave) * 64;       // chunk base (16B units)
            int chunk = cb + lane;              // 0..1023
            int row = chunk >> 3;               // 0..127
            int sc = ((chunk & 7) * 16) ^ ((row & 7) << 4);
            const char* gA = (const char*)(A + (m0 + row) * (long)K + k0) + sc;
            const char* gB = (const char*)(Bw + (n0 + row) * (long)K + k0) + sc;
            gload_lds16(gA, (char*)sA + cb * 16);
            gload_lds16(gB, (char*)sB + cb * 16);
        }
        __syncthreads();
        #pragma unroll
        for (int s = 0; s < 2; ++s) {
            bf16x8 af[4], bfr[4];
            #pragma unroll
            for (int m = 0; m < 4; ++m) {
                int row = wr * 64 + m * 16 + c;
                int kb = (s * 64 + g * 16) ^ ((row & 7) << 4);
                af[m] = *(const bf16x8*)((const char*)sA + row * 128 + kb);
            }
            #pragma unroll
            for (int n = 0; n < 4; ++n) {
                int row = wc * 64 + n * 16 + c;
                int kb = (s * 64 + g * 16) ^ ((row & 7) << 4);
                bfr[n] = *(const bf16x8*)((const char*)sB + row * 128 + kb);
            }
            #pragma unroll
            for (int m = 0; m < 4; ++m)
                #pragma unroll
                for (int n = 0; n < 4; ++n)
                    acc[m][n] = __builtin_amdgcn_mfma_f32_16x16x32_bf16(
                        af[m], bfr[n], acc[m][n], 0, 0, 0);
        }
        __syncthreads();
    }

    #pragma unroll
    for (int m = 0; m < 4; ++m) {
        #pragma unroll
        for (int n = 0; n < 4; ++n) {
            long col = n0 + wc * 64 + n * 16 + c;
            float bv = bias[col];
            #pragma unroll
            for (int r = 0; r < 4; ++r) {
                long row = m0 + wr * 64 + m * 16 + g * 4 + r;
                float v = acc[m][n][r] + bv;
                if (BF16_OUT)
                    ((__hip_bfloat16*)Cv)[row * N + col] = __float2bfloat16(v);
                else
                    ((float*)Cv)[row * N + col] = v;
            }
        }
    }
}

// ---------------- fused causal attention with alibi + phylo temp ----------------
// block: (qtile of 64 rows, head, batch); 4 waves x 16 q-rows.
__global__ __launch_bounds__(256, 2)
void attn_kernel(const __hip_bfloat16* __restrict__ qkv,   // [B*L, 3072]
                 const float* __restrict__ alibi,          // [H, L, L]
                 const float* __restrict__ scales,         // [B]
                 __hip_bfloat16* __restrict__ out) {       // [B*L, 1024]
    __shared__ short sK[32 * 64];        // swizzled [32 kv][64 hd]
    __shared__ short sVt[64 * 40];       // [64 d][32 kv + 8 pad]
    __shared__ short sP[4][16 * 40];     // per-wave [16 q][32 kv + 8 pad]

    const int qt = blockIdx.x, h = blockIdx.y, b = blockIdx.z;
    const int q0 = qt * 64;
    const int tid = threadIdx.x;
    const int wave = tid >> 6, lane = tid & 63;
    const int g = lane >> 4, c = lane & 15;
    const int qw0 = q0 + wave * 16;
    const float scale = scales[b];

    const long base_bl = (long)b * 2048;
    const __hip_bfloat16* qrow = qkv + (base_bl + qw0 + c) * 3072 + h * 64;
    bf16x8 qf0 = *(const bf16x8*)(qrow + g * 8);
    bf16x8 qf1 = *(const bf16x8*)(qrow + 32 + g * 8);

    const __hip_bfloat16* kg = qkv + base_bl * 3072 + 1024 + h * 64;
    const __hip_bfloat16* vg = qkv + base_bl * 3072 + 2048 + h * 64;
    const float* ab_base = alibi + (long)h * 2048 * 2048;

    f32x4 acc_o[4];
    #pragma unroll
    for (int d = 0; d < 4; ++d) acc_o[d] = f32x4{0.f, 0.f, 0.f, 0.f};
    float mrow[4] = {-3e38f, -3e38f, -3e38f, -3e38f};
    float lrow[4] = {0.f, 0.f, 0.f, 0.f};

    short* sPw = &sP[wave][0];

    for (int kv0 = 0; kv0 < q0 + 64; kv0 += 32) {
        if (wave >= 2) {
            // stage K tile [32][64] via global_load_lds, swizzled source
            #pragma unroll
            for (int i = 0; i < 2; ++i) {
                int cb = ((wave - 2) * 2 + i) * 64;     // chunk base
                int chunk = cb + lane;                  // 0..255
                int row = chunk >> 3;                   // 0..31
                int sc = ((chunk & 7) * 16) ^ ((row & 7) << 4);
                const char* src = (const char*)(kg + (long)(kv0 + row) * 3072) + sc;
                gload_lds16(src, (char*)sK + cb * 16);
            }
        } else {
            // transpose-stage V tile -> sVt[d][kv], packed pair writes
            int t = wave * 64 + lane;       // 0..127
            int p2 = t & 15;                // kv pair index
            int d0 = ((t >> 4) & 7) * 8;
            const __hip_bfloat16* v0p = vg + (long)(kv0 + 2 * p2) * 3072 + d0;
            bf16x8 va = *(const bf16x8*)v0p;
            bf16x8 vb = *(const bf16x8*)(v0p + 3072);
            #pragma unroll
            for (int j = 0; j < 8; ++j) {
                unsigned pk = ((unsigned)(unsigned short)va[j]) |
                              (((unsigned)(unsigned short)vb[j]) << 16);
                *(unsigned*)((char*)sVt + (d0 + j) * 80 + p2 * 4) = pk;
            }
        }
        __syncthreads();

        if (kv0 <= qw0 + 15) {   // wave-uniform participation
            float ab[2][4];
            #pragma unroll
            for (int s2 = 0; s2 < 2; ++s2)
                #pragma unroll
                for (int r = 0; r < 4; ++r)
                    ab[s2][r] = ab_base[(long)(qw0 + g * 4 + r) * 2048 +
                                        (kv0 + s2 * 16 + c)];

            f32x4 accs[2];
            accs[0] = f32x4{0.f, 0.f, 0.f, 0.f};
            accs[1] = f32x4{0.f, 0.f, 0.f, 0.f};
            #pragma unroll
            for (int s2 = 0; s2 < 2; ++s2) {
                int row = s2 * 16 + c;
                int swz = (row & 7) << 4;
                bf16x8 kf0 = *(const bf16x8*)((const char*)sK + row * 128 + ((g * 16) ^ swz));
                bf16x8 kf1 = *(const bf16x8*)((const char*)sK + row * 128 + ((64 + g * 16) ^ swz));
                accs[s2] = __builtin_amdgcn_mfma_f32_16x16x32_bf16(qf0, kf0, accs[s2], 0, 0, 0);
                accs[s2] = __builtin_amdgcn_mfma_f32_16x16x32_bf16(qf1, kf1, accs[s2], 0, 0, 0);
            }

            #pragma unroll
            for (int r = 0; r < 4; ++r) {
                int qi = qw0 + g * 4 + r;
                float s0 = accs[0][r] * scale + ab[0][r];
                float s1 = accs[1][r] * scale + ab[1][r];
                if (kv0 + c > qi) s0 = -1e30f;
                if (kv0 + 16 + c > qi) s1 = -1e30f;
                float mx = fmaxf(s0, s1);
                mx = fmaxf(mx, __shfl_xor(mx, 1));
                mx = fmaxf(mx, __shfl_xor(mx, 2));
                mx = fmaxf(mx, __shfl_xor(mx, 4));
                mx = fmaxf(mx, __shfl_xor(mx, 8));
                float mn = fmaxf(mrow[r], mx);
                float alpha = __expf(mrow[r] - mn);
                mrow[r] = mn;
                float p0 = __expf(s0 - mn);
                float p1 = __expf(s1 - mn);
                float rs = p0 + p1;
                rs += __shfl_xor(rs, 1);
                rs += __shfl_xor(rs, 2);
                rs += __shfl_xor(rs, 4);
                rs += __shfl_xor(rs, 8);
                lrow[r] = lrow[r] * alpha + rs;
                #pragma unroll
                for (int d = 0; d < 4; ++d) acc_o[d][r] *= alpha;
                sPw[(g * 4 + r) * 40 + c] = f2bf(p0);
                sPw[(g * 4 + r) * 40 + 16 + c] = f2bf(p1);
            }
            asm volatile("s_waitcnt lgkmcnt(0)" ::: "memory");
            bf16x8 pf = *(const bf16x8*)((const char*)sPw + c * 80 + g * 16);
            #pragma unroll
            for (int d = 0; d < 4; ++d) {
                bf16x8 vf = *(const bf16x8*)((const char*)sVt + (d * 16 + c) * 80 + g * 16);
                acc_o[d] = __builtin_amdgcn_mfma_f32_16x16x32_bf16(pf, vf, acc_o[d], 0, 0, 0);
            }
        }
        __syncthreads();
    }

    __hip_bfloat16* op = out + (base_bl + qw0 + g * 4) * 1024 + h * 64;
    #pragma unroll
    for (int r = 0; r < 4; ++r) {
        float inv = 1.0f / lrow[r];
        #pragma unroll
        for (int d = 0; d < 4; ++d)
            op[(long)r * 1024 + d * 16 + c] = __float2bfloat16(acc_o[d][r] * inv);
    }
}

extern "C" void kernel_launch(void* const* d_in, const int* in_sizes, int n_in,
                              void* d_out, int out_size, void* d_ws, size_t ws_size,
                              hipStream_t stream) {
    const float* x      = (const float*)d_in[0];
    const float* phylo  = (const float*)d_in[1];
    const float* alibi  = (const float*)d_in[2];
    // d_in[3] = attn_mask (causal, recomputed on device — ignored)
    const float* qkv_w  = (const float*)d_in[4];
    const float* qkv_b  = (const float*)d_in[5];
    const float* out_w  = (const float*)d_in[6];
    const float* out_b  = (const float*)d_in[7];
    const float* alphap = (const float*)d_in[8];

    char* ws = (char*)d_ws;
    __hip_bfloat16* xbf   = (__hip_bfloat16*)(ws);                 // 8 MB
    __hip_bfloat16* qwbf  = (__hip_bfloat16*)(ws + (8l << 20));    // 6 MB
    __hip_bfloat16* owbf  = (__hip_bfloat16*)(ws + (14l << 20));   // 2 MB
    __hip_bfloat16* qkvbf = (__hip_bfloat16*)(ws + (16l << 20));   // 24 MB
    __hip_bfloat16* aobf  = (__hip_bfloat16*)(ws + (40l << 20));   // 8 MB
    float* scales         = (float*)(ws + (48l << 20));            // 2 floats

    cvt_kernel<<<2048, 256, 0, stream>>>(x, xbf, 4096 * 1024 / 4);
    cvt_kernel<<<2048, 256, 0, stream>>>(qkv_w, qwbf, 3072 * 1024 / 4);
    cvt_kernel<<<1024, 256, 0, stream>>>(out_w, owbf, 1024 * 1024 / 4);
    scale_kernel<<<2, 256, 0, stream>>>(phylo, alphap, scales);

    gemm_nt<1><<<dim3(24, 32), 256, 0, stream>>>(xbf, qwbf, qkv_b, qkvbf,
                                                 4096, 3072, 1024);
    attn_kernel<<<dim3(32, 16, 2), 256, 0, stream>>>(qkvbf, alibi, scales, aobf);
    gemm_nt<0><<<dim3(8, 32), 256, 0, stream>>>(aobf, owbf, out_b, d_out,
                                                4096, 1024, 1024);
}

// Round 2
// 162.373 us; speedup vs baseline: 1.5132x; 1.5132x over previous
//
#include <hip/hip_runtime.h>
#include <hip/hip_bf16.h>

typedef __attribute__((ext_vector_type(8))) short bf16x8;
typedef __attribute__((ext_vector_type(4))) float f32x4;
typedef __attribute__((ext_vector_type(4))) float f4v;
typedef __attribute__((ext_vector_type(4))) short s4v;

__device__ __forceinline__ short f2bf(float f) {
    union { __hip_bfloat16 h; short s; } u;
    u.h = __float2bfloat16(f);
    return u.s;
}

__device__ __forceinline__ void gload_lds16(const void* g, void* l) {
    __builtin_amdgcn_global_load_lds(
        (const __attribute__((address_space(1))) void*)g,
        (__attribute__((address_space(3))) void*)l,
        16, 0, 0);
}

// ---------------- f32 -> bf16 conversion ----------------
__global__ void cvt_kernel(const float* __restrict__ in,
                           __hip_bfloat16* __restrict__ out, int n4) {
    int i = blockIdx.x * blockDim.x + threadIdx.x;
    int stride = gridDim.x * blockDim.x;
    for (; i < n4; i += stride) {
        f4v v = ((const f4v*)in)[i];
        s4v o;
        #pragma unroll
        for (int j = 0; j < 4; ++j) o[j] = f2bf(v[j]);
        ((s4v*)out)[i] = o;
    }
}

// ---------------- per-batch scale ----------------
__global__ void scale_kernel(const float* __restrict__ pd,
                             const float* __restrict__ alphap,
                             float* __restrict__ scales) {
    int b = blockIdx.x;
    float s = 0.f;
    for (int i = threadIdx.x; i < 2048; i += 256) s += pd[b * 2048 + i];
    for (int o = 32; o; o >>= 1) s += __shfl_down(s, o);
    __shared__ float wsum[4];
    if ((threadIdx.x & 63) == 0) wsum[threadIdx.x >> 6] = s;
    __syncthreads();
    if (threadIdx.x == 0) {
        float t = wsum[0] + wsum[1] + wsum[2] + wsum[3];
        float mean = t * (1.0f / 2048.0f);
        float temp = fmaxf(1.0f + alphap[0] * mean, 1e-6f);
        scales[b] = 0.125f * temp;   // SCALE = 64^-0.5
    }
}

// ---------------- NT GEMM: C[M,N] = A[M,K] * B[N,K]^T + bias ----------------
template<int BF16_OUT>
__global__ __launch_bounds__(256, 2)
void gemm_nt(const __hip_bfloat16* __restrict__ A,
             const __hip_bfloat16* __restrict__ Bw,
             const float* __restrict__ bias,
             void* __restrict__ Cv,
             int M, int N, int K) {
    __shared__ short sA[128 * 64];
    __shared__ short sB[128 * 64];
    const int tid = threadIdx.x;
    const int wave = tid >> 6, lane = tid & 63;
    const int g = lane >> 4, c = lane & 15;
    const int wr = wave >> 1, wc = wave & 1;
    const long m0 = (long)blockIdx.y * 128, n0 = (long)blockIdx.x * 128;

    f32x4 acc[4][4];
    #pragma unroll
    for (int m = 0; m < 4; ++m)
        #pragma unroll
        for (int n = 0; n < 4; ++n) acc[m][n] = f32x4{0.f, 0.f, 0.f, 0.f};

    for (int k0 = 0; k0 < K; k0 += 64) {
        #pragma unroll
        for (int i = 0; i < 4; ++i) {
            int cb = (i * 4 + wave) * 64;
            int chunk = cb + lane;
            int row = chunk >> 3;
            int sc = ((chunk & 7) * 16) ^ ((row & 7) << 4);
            const char* gA = (const char*)(A + (m0 + row) * (long)K + k0) + sc;
            const char* gB = (const char*)(Bw + (n0 + row) * (long)K + k0) + sc;
            gload_lds16(gA, (char*)sA + cb * 16);
            gload_lds16(gB, (char*)sB + cb * 16);
        }
        __syncthreads();
        #pragma unroll
        for (int s = 0; s < 2; ++s) {
            bf16x8 af[4], bfr[4];
            #pragma unroll
            for (int m = 0; m < 4; ++m) {
                int row = wr * 64 + m * 16 + c;
                int kb = (s * 64 + g * 16) ^ ((row & 7) << 4);
                af[m] = *(const bf16x8*)((const char*)sA + row * 128 + kb);
            }
            #pragma unroll
            for (int n = 0; n < 4; ++n) {
                int row = wc * 64 + n * 16 + c;
                int kb = (s * 64 + g * 16) ^ ((row & 7) << 4);
                bfr[n] = *(const bf16x8*)((const char*)sB + row * 128 + kb);
            }
            #pragma unroll
            for (int m = 0; m < 4; ++m)
                #pragma unroll
                for (int n = 0; n < 4; ++n)
                    acc[m][n] = __builtin_amdgcn_mfma_f32_16x16x32_bf16(
                        af[m], bfr[n], acc[m][n], 0, 0, 0);
        }
        __syncthreads();
    }

    #pragma unroll
    for (int m = 0; m < 4; ++m) {
        #pragma unroll
        for (int n = 0; n < 4; ++n) {
            long col = n0 + wc * 64 + n * 16 + c;
            float bv = bias[col];
            #pragma unroll
            for (int r = 0; r < 4; ++r) {
                long row = m0 + wr * 64 + m * 16 + g * 4 + r;
                float v = acc[m][n][r] + bv;
                if (BF16_OUT)
                    ((__hip_bfloat16*)Cv)[row * N + col] = __float2bfloat16(v);
                else
                    ((float*)Cv)[row * N + col] = v;
            }
        }
    }
}

// ---------------- attention v2 ----------------
// Paired q-tiles {p, 31-p} share K/V staging. KVBLK=64, double-buffered,
// 4 waves x 16 q-rows per tile, alibi register-prefetched 1 iter ahead.

__device__ __forceinline__ void stage_kv(
    const __hip_bfloat16* kg, const __hip_bfloat16* vg, int kv0,
    short* sKbuf, short* sVtbuf, int wave, int lane, int tid)
{
    #pragma unroll
    for (int i = 0; i < 2; ++i) {
        int cb = (i * 4 + wave) * 64;          // chunk base, 512 chunks total
        int chunk = cb + lane;
        int row = chunk >> 3;                  // 0..63
        int sc = ((chunk & 7) * 16) ^ ((row & 7) << 4);
        const char* src = (const char*)(kg + (long)(kv0 + row) * 3072) + sc;
        gload_lds16(src, (char*)sKbuf + cb * 16);
    }
    // V transpose: thread -> kv pair p2 (0..31), d-group d0 (0,8,..56)
    int p2 = tid & 31;
    int d0 = (tid >> 5) * 8;
    const __hip_bfloat16* v0p = vg + (long)(kv0 + 2 * p2) * 3072 + d0;
    bf16x8 va = *(const bf16x8*)v0p;
    bf16x8 vb = *(const bf16x8*)(v0p + 3072);
    #pragma unroll
    for (int j = 0; j < 8; ++j) {
        unsigned pk = ((unsigned)(unsigned short)va[j]) |
                      (((unsigned)(unsigned short)vb[j]) << 16);
        *(unsigned*)((char*)sVtbuf + (d0 + j) * 144 + p2 * 4) = pk;
    }
}

__device__ __forceinline__ void compute_tile(
    const short* sKc, const short* sVtc, short* sPw,
    bf16x8 qf0, bf16x8 qf1,
    f32x4 (&acc_o)[4], float (&m)[4], float (&l)[4],
    const float (&ab)[4][4],
    float scale, int qi0, int kv0, bool diag, int g, int c)
{
    f32x4 accs[4];
    #pragma unroll
    for (int nf = 0; nf < 4; ++nf) accs[nf] = f32x4{0.f, 0.f, 0.f, 0.f};
    const int swz = (c & 7) << 4;
    #pragma unroll
    for (int nf = 0; nf < 4; ++nf) {
        int row = nf * 16 + c;
        const char* kb = (const char*)sKc + row * 128;
        bf16x8 kf0 = *(const bf16x8*)(kb + ((g * 16) ^ swz));
        bf16x8 kf1 = *(const bf16x8*)(kb + ((64 + g * 16) ^ swz));
        accs[nf] = __builtin_amdgcn_mfma_f32_16x16x32_bf16(qf0, kf0, accs[nf], 0, 0, 0);
        accs[nf] = __builtin_amdgcn_mfma_f32_16x16x32_bf16(qf1, kf1, accs[nf], 0, 0, 0);
    }
    #pragma unroll
    for (int r = 0; r < 4; ++r) {
        int qi = qi0 + r;
        float s[4];
        #pragma unroll
        for (int nf = 0; nf < 4; ++nf) {
            s[nf] = accs[nf][r] * scale + ab[nf][r];
            if (diag && (kv0 + nf * 16 + c > qi)) s[nf] = -1e30f;
        }
        float mx = fmaxf(fmaxf(s[0], s[1]), fmaxf(s[2], s[3]));
        mx = fmaxf(mx, __shfl_xor(mx, 1));
        mx = fmaxf(mx, __shfl_xor(mx, 2));
        mx = fmaxf(mx, __shfl_xor(mx, 4));
        mx = fmaxf(mx, __shfl_xor(mx, 8));
        float mn = fmaxf(m[r], mx);
        float alpha = __expf(m[r] - mn);
        m[r] = mn;
        float ps = 0.f;
        #pragma unroll
        for (int nf = 0; nf < 4; ++nf) {
            float pv = __expf(s[nf] - mn);
            ps += pv;
            sPw[(g * 4 + r) * 72 + nf * 16 + c] = f2bf(pv);
        }
        ps += __shfl_xor(ps, 1);
        ps += __shfl_xor(ps, 2);
        ps += __shfl_xor(ps, 4);
        ps += __shfl_xor(ps, 8);
        l[r] = l[r] * alpha + ps;
        #pragma unroll
        for (int d = 0; d < 4; ++d) acc_o[d][r] *= alpha;
    }
    asm volatile("s_waitcnt lgkmcnt(0)" ::: "memory");
    bf16x8 pf0 = *(const bf16x8*)((const char*)sPw + c * 144 + g * 16);
    bf16x8 pf1 = *(const bf16x8*)((const char*)sPw + c * 144 + 64 + g * 16);
    #pragma unroll
    for (int d = 0; d < 4; ++d) {
        const char* vb = (const char*)sVtc + (d * 16 + c) * 144;
        bf16x8 vf0 = *(const bf16x8*)(vb + g * 16);
        bf16x8 vf1 = *(const bf16x8*)(vb + 64 + g * 16);
        acc_o[d] = __builtin_amdgcn_mfma_f32_16x16x32_bf16(pf0, vf0, acc_o[d], 0, 0, 0);
        acc_o[d] = __builtin_amdgcn_mfma_f32_16x16x32_bf16(pf1, vf1, acc_o[d], 0, 0, 0);
    }
}

__global__ __launch_bounds__(256, 2)
void attn_kernel(const __hip_bfloat16* __restrict__ qkv,   // [B*L, 3072]
                 const float* __restrict__ alibi,          // [H, L, L]
                 const float* __restrict__ scales,         // [B]
                 __hip_bfloat16* __restrict__ out) {       // [B*L, 1024]
    __shared__ short sK[2][64 * 64];      // swizzled [64 kv][64 hd]
    __shared__ short sVt[2][64 * 72];     // [64 d][64 kv + 8 pad]
    __shared__ short sPA[4][16 * 72];
    __shared__ short sPB[4][16 * 72];

    const int p = blockIdx.x, h = blockIdx.y, b = blockIdx.z;
    const int qtA = p, qtB = 31 - p;
    const int nIter = qtB + 1;
    const int tid = threadIdx.x;
    const int wave = tid >> 6, lane = tid & 63;
    const int g = lane >> 4, c = lane & 15;
    const float scale = scales[b];
    const long base_bl = (long)b * 2048;

    const int qA0 = qtA * 64 + wave * 16;
    const int qB0 = qtB * 64 + wave * 16;

    const __hip_bfloat16* qrowA = qkv + (base_bl + qA0 + c) * 3072 + h * 64;
    const __hip_bfloat16* qrowB = qkv + (base_bl + qB0 + c) * 3072 + h * 64;
    bf16x8 qAf0 = *(const bf16x8*)(qrowA + g * 8);
    bf16x8 qAf1 = *(const bf16x8*)(qrowA + 32 + g * 8);
    bf16x8 qBf0 = *(const bf16x8*)(qrowB + g * 8);
    bf16x8 qBf1 = *(const bf16x8*)(qrowB + 32 + g * 8);

    const __hip_bfloat16* kg = qkv + base_bl * 3072 + 1024 + h * 64;
    const __hip_bfloat16* vg = qkv + base_bl * 3072 + 2048 + h * 64;
    const float* abA_base = alibi + (long)h * 2048 * 2048 + (long)(qA0 + g * 4) * 2048;
    const float* abB_base = alibi + (long)h * 2048 * 2048 + (long)(qB0 + g * 4) * 2048;

    f32x4 accA[4], accB[4];
    float mA[4], lA[4], mB[4], lB[4];
    #pragma unroll
    for (int d = 0; d < 4; ++d) {
        accA[d] = f32x4{0.f, 0.f, 0.f, 0.f};
        accB[d] = f32x4{0.f, 0.f, 0.f, 0.f};
    }
    #pragma unroll
    for (int r = 0; r < 4; ++r) {
        mA[r] = -3e38f; lA[r] = 0.f;
        mB[r] = -3e38f; lB[r] = 0.f;
    }

    float abA[4][4], abB[4][4], abAn[4][4], abBn[4][4];
    stage_kv(kg, vg, 0, sK[0], sVt[0], wave, lane, tid);
    #pragma unroll
    for (int nf = 0; nf < 4; ++nf)
        #pragma unroll
        for (int r = 0; r < 4; ++r) {
            abA[nf][r] = abA_base[(long)r * 2048 + nf * 16 + c];
            abB[nf][r] = abB_base[(long)r * 2048 + nf * 16 + c];
            abAn[nf][r] = 0.f; abBn[nf][r] = 0.f;
        }
    __syncthreads();

    for (int t = 0; t < nIter; ++t) {
        const int cur = t & 1;
        const int kv0 = t * 64;
        if (t + 1 < nIter) {
            stage_kv(kg, vg, kv0 + 64, sK[cur ^ 1], sVt[cur ^ 1], wave, lane, tid);
            #pragma unroll
            for (int nf = 0; nf < 4; ++nf)
                #pragma unroll
                for (int r = 0; r < 4; ++r)
                    abBn[nf][r] = abB_base[(long)r * 2048 + kv0 + 64 + nf * 16 + c];
        }
        if (t + 1 <= qtA) {
            #pragma unroll
            for (int nf = 0; nf < 4; ++nf)
                #pragma unroll
                for (int r = 0; r < 4; ++r)
                    abAn[nf][r] = abA_base[(long)r * 2048 + kv0 + 64 + nf * 16 + c];
        }

        compute_tile(sK[cur], sVt[cur], &sPB[wave][0], qBf0, qBf1,
                     accB, mB, lB, abB, scale, qB0 + g * 4, kv0, t == qtB, g, c);
        if (t <= qtA)
            compute_tile(sK[cur], sVt[cur], &sPA[wave][0], qAf0, qAf1,
                         accA, mA, lA, abA, scale, qA0 + g * 4, kv0, t == qtA, g, c);

        __syncthreads();
        #pragma unroll
        for (int nf = 0; nf < 4; ++nf)
            #pragma unroll
            for (int r = 0; r < 4; ++r) {
                abA[nf][r] = abAn[nf][r];
                abB[nf][r] = abBn[nf][r];
            }
    }

    __hip_bfloat16* opA = out + (base_bl + qA0 + g * 4) * 1024 + h * 64;
    __hip_bfloat16* opB = out + (base_bl + qB0 + g * 4) * 1024 + h * 64;
    #pragma unroll
    for (int r = 0; r < 4; ++r) {
        float invA = 1.0f / lA[r];
        float invB = 1.0f / lB[r];
        #pragma unroll
        for (int d = 0; d < 4; ++d) {
            opA[(long)r * 1024 + d * 16 + c] = __float2bfloat16(accA[d][r] * invA);
            opB[(long)r * 1024 + d * 16 + c] = __float2bfloat16(accB[d][r] * invB);
        }
    }
}

extern "C" void kernel_launch(void* const* d_in, const int* in_sizes, int n_in,
                              void* d_out, int out_size, void* d_ws, size_t ws_size,
                              hipStream_t stream) {
    const float* x      = (const float*)d_in[0];
    const float* phylo  = (const float*)d_in[1];
    const float* alibi  = (const float*)d_in[2];
    const float* qkv_w  = (const float*)d_in[4];
    const float* qkv_b  = (const float*)d_in[5];
    const float* out_w  = (const float*)d_in[6];
    const float* out_b  = (const float*)d_in[7];
    const float* alphap = (const float*)d_in[8];

    char* ws = (char*)d_ws;
    __hip_bfloat16* xbf   = (__hip_bfloat16*)(ws);                 // 8 MB
    __hip_bfloat16* qwbf  = (__hip_bfloat16*)(ws + (8l << 20));    // 6 MB
    __hip_bfloat16* owbf  = (__hip_bfloat16*)(ws + (14l << 20));   // 2 MB
    __hip_bfloat16* qkvbf = (__hip_bfloat16*)(ws + (16l << 20));   // 24 MB
    __hip_bfloat16* aobf  = (__hip_bfloat16*)(ws + (40l << 20));   // 8 MB
    float* scales         = (float*)(ws + (48l << 20));            // 2 floats

    cvt_kernel<<<2048, 256, 0, stream>>>(x, xbf, 4096 * 1024 / 4);
    cvt_kernel<<<2048, 256, 0, stream>>>(qkv_w, qwbf, 3072 * 1024 / 4);
    cvt_kernel<<<1024, 256, 0, stream>>>(out_w, owbf, 1024 * 1024 / 4);
    scale_kernel<<<2, 256, 0, stream>>>(phylo, alphap, scales);

    gemm_nt<1><<<dim3(24, 32), 256, 0, stream>>>(xbf, qwbf, qkv_b, qkvbf,
                                                 4096, 3072, 1024);
    attn_kernel<<<dim3(16, 16, 2), 256, 0, stream>>>(qkvbf, alibi, scales, aobf);
    gemm_nt<0><<<dim3(8, 32), 256, 0, stream>>>(aobf, owbf, out_b, d_out,
                                                4096, 1024, 1024);
}

// Round 3
// 135.369 us; speedup vs baseline: 1.8151x; 1.1995x over previous
//
#include <hip/hip_runtime.h>
#include <hip/hip_bf16.h>

typedef __attribute__((ext_vector_type(8))) short bf16x8;
typedef __attribute__((ext_vector_type(4))) float f32x4;
typedef __attribute__((ext_vector_type(4))) float f4v;
typedef __attribute__((ext_vector_type(4))) short s4v;

__device__ __forceinline__ short f2bf(float f) {
    union { __hip_bfloat16 h; short s; } u;
    u.h = __float2bfloat16(f);
    return u.s;
}

__device__ __forceinline__ void gload_lds16(const void* g, void* l) {
    __builtin_amdgcn_global_load_lds(
        (const __attribute__((address_space(1))) void*)g,
        (__attribute__((address_space(3))) void*)l,
        16, 0, 0);
}

#define MFMA16(a, b, c) __builtin_amdgcn_mfma_f32_16x16x32_bf16((a), (b), (c), 0, 0, 0)

// ---------------- fused prep: 3x f32->bf16 cvt + per-batch scale ----------------
__global__ void prep_kernel(const float* __restrict__ x,
                            const float* __restrict__ qw,
                            const float* __restrict__ ow,
                            const float* __restrict__ pd,
                            const float* __restrict__ alphap,
                            s4v* __restrict__ xb, s4v* __restrict__ qb,
                            s4v* __restrict__ ob, float* __restrict__ scales) {
    __shared__ float wsum[4];
    if (blockIdx.x >= 2048) {
        int b = blockIdx.x - 2048;
        float s = 0.f;
        for (int i = threadIdx.x; i < 2048; i += 256) s += pd[b * 2048 + i];
        for (int o = 32; o; o >>= 1) s += __shfl_down(s, o);
        if ((threadIdx.x & 63) == 0) wsum[threadIdx.x >> 6] = s;
        __syncthreads();
        if (threadIdx.x == 0) {
            float t = wsum[0] + wsum[1] + wsum[2] + wsum[3];
            float mean = t * (1.0f / 2048.0f);
            float temp = fmaxf(1.0f + alphap[0] * mean, 1e-6f);
            scales[b] = 0.125f * temp;
        }
        return;
    }
    // regions (in float4 units): x 1048576, qkv_w 786432, out_w 262144
    #pragma unroll
    for (int j = 0; j < 4; ++j) {
        int idx = blockIdx.x * 1024 + j * 256 + threadIdx.x;
        const f4v* src;
        s4v* dst;
        int off;
        if (idx < 1048576)      { src = (const f4v*)x;  dst = xb; off = idx; }
        else if (idx < 1835008) { src = (const f4v*)qw; dst = qb; off = idx - 1048576; }
        else                    { src = (const f4v*)ow; dst = ob; off = idx - 1835008; }
        f4v v = src[off];
        s4v o;
        #pragma unroll
        for (int k = 0; k < 4; ++k) o[k] = f2bf(v[k]);
        dst[off] = o;
    }
}

// ---------------- NT GEMM: C[M,N] = A[M,K] * B[N,K]^T + bias ----------------
// 128 x (NF*32) tile, BK=64, 256 threads (4 waves, 2x2), swizzled LDS staging.
template<int BF16_OUT, int NF>
__global__ __launch_bounds__(256, 2)
void gemm_nt(const __hip_bfloat16* __restrict__ A,
             const __hip_bfloat16* __restrict__ Bw,
             const float* __restrict__ bias,
             void* __restrict__ Cv,
             int M, int N, int K) {
    __shared__ short sA[128 * 64];
    __shared__ short sB[NF * 32 * 64];
    const int tid = threadIdx.x;
    const int wave = tid >> 6, lane = tid & 63;
    const int g = lane >> 4, c = lane & 15;
    const int wr = wave >> 1, wc = wave & 1;
    const long m0 = (long)blockIdx.y * 128, n0 = (long)blockIdx.x * (NF * 32);

    f32x4 acc[4][NF];
    #pragma unroll
    for (int m = 0; m < 4; ++m)
        #pragma unroll
        for (int n = 0; n < NF; ++n) acc[m][n] = f32x4{0.f, 0.f, 0.f, 0.f};

    for (int k0 = 0; k0 < K; k0 += 64) {
        #pragma unroll
        for (int i = 0; i < 4; ++i) {
            int cb = (i * 4 + wave) * 64;
            int chunk = cb + lane;
            int row = chunk >> 3;
            int sc = ((chunk & 7) * 16) ^ ((row & 7) << 4);
            const char* gA = (const char*)(A + (m0 + row) * (long)K + k0) + sc;
            gload_lds16(gA, (char*)sA + cb * 16);
        }
        #pragma unroll
        for (int i = 0; i < NF; ++i) {
            int cb = (i * 4 + wave) * 64;
            int chunk = cb + lane;
            int row = chunk >> 3;
            int sc = ((chunk & 7) * 16) ^ ((row & 7) << 4);
            const char* gB = (const char*)(Bw + (n0 + row) * (long)K + k0) + sc;
            gload_lds16(gB, (char*)sB + cb * 16);
        }
        __syncthreads();
        #pragma unroll
        for (int s = 0; s < 2; ++s) {
            bf16x8 af[4], bfr[NF];
            #pragma unroll
            for (int m = 0; m < 4; ++m) {
                int row = wr * 64 + m * 16 + c;
                int kb = (s * 64 + g * 16) ^ ((row & 7) << 4);
                af[m] = *(const bf16x8*)((const char*)sA + row * 128 + kb);
            }
            #pragma unroll
            for (int n = 0; n < NF; ++n) {
                int row = wc * (NF * 16) + n * 16 + c;
                int kb = (s * 64 + g * 16) ^ ((row & 7) << 4);
                bfr[n] = *(const bf16x8*)((const char*)sB + row * 128 + kb);
            }
            #pragma unroll
            for (int m = 0; m < 4; ++m)
                #pragma unroll
                for (int n = 0; n < NF; ++n)
                    acc[m][n] = MFMA16(af[m], bfr[n], acc[m][n]);
        }
        __syncthreads();
    }

    #pragma unroll
    for (int m = 0; m < 4; ++m) {
        #pragma unroll
        for (int n = 0; n < NF; ++n) {
            long col = n0 + wc * (NF * 16) + n * 16 + c;
            float bv = bias[col];
            #pragma unroll
            for (int r = 0; r < 4; ++r) {
                long row = m0 + wr * 64 + m * 16 + g * 4 + r;
                float v = acc[m][n][r] + bv;
                if (BF16_OUT)
                    ((__hip_bfloat16*)Cv)[row * N + col] = __float2bfloat16(v);
                else
                    ((float*)Cv)[row * N + col] = v;
            }
        }
    }
}

// ---------------- attention v3 ----------------
// Paired q-tiles {p, 31-p} share K/V staging. KVBLK=64, double-buffered.
// Deferred-max softmax (THR=8), row-sum via MFMA ones-operand, async V staging.

__device__ __forceinline__ void compute_tile(
    const bf16x8 (&kf)[4][2], const short* sVtc, short* sPw,
    bf16x8 qf0, bf16x8 qf1,
    f32x4 (&acc_o)[4], f32x4& accL, float (&m)[4],
    const float (&ab)[4][4],
    float scale, int qi0, int kv0, bool diag, int g, int c)
{
    f32x4 accs[4];
    #pragma unroll
    for (int nf = 0; nf < 4; ++nf) {
        accs[nf] = f32x4{0.f, 0.f, 0.f, 0.f};
        accs[nf] = MFMA16(qf0, kf[nf][0], accs[nf]);
        accs[nf] = MFMA16(qf1, kf[nf][1], accs[nf]);
    }
    float s[4][4], pmax[4];
    bool ok = true;
    #pragma unroll
    for (int r = 0; r < 4; ++r) {
        int qi = qi0 + r;
        #pragma unroll
        for (int nf = 0; nf < 4; ++nf) {
            float sv = fmaf(accs[nf][r], scale, ab[nf][r]);
            if (diag && (kv0 + nf * 16 + c > qi)) sv = -1e30f;
            s[r][nf] = sv;
        }
        pmax[r] = fmaxf(fmaxf(s[r][0], s[r][1]), fmaxf(s[r][2], s[r][3]));
        ok = ok && (pmax[r] <= m[r] + 8.0f);
    }
    if (!__all(ok)) {   // rare after first tile: full max-reduce + rescale
        #pragma unroll
        for (int r = 0; r < 4; ++r) {
            float mx = pmax[r];
            mx = fmaxf(mx, __shfl_xor(mx, 1));
            mx = fmaxf(mx, __shfl_xor(mx, 2));
            mx = fmaxf(mx, __shfl_xor(mx, 4));
            mx = fmaxf(mx, __shfl_xor(mx, 8));
            float mn = fmaxf(m[r], mx);
            float alpha = __expf(m[r] - mn);
            m[r] = mn;
            accL[r] *= alpha;
            #pragma unroll
            for (int d = 0; d < 4; ++d) acc_o[d][r] *= alpha;
        }
    }
    #pragma unroll
    for (int r = 0; r < 4; ++r)
        #pragma unroll
        for (int nf = 0; nf < 4; ++nf)
            sPw[(g * 4 + r) * 72 + nf * 16 + c] = f2bf(__expf(s[r][nf] - m[r]));
    asm volatile("s_waitcnt lgkmcnt(0)" ::: "memory");
    bf16x8 pf0 = *(const bf16x8*)((const char*)sPw + c * 144 + g * 16);
    bf16x8 pf1 = *(const bf16x8*)((const char*)sPw + c * 144 + 64 + g * 16);
    const short ONE = 0x3F80;
    const bf16x8 ones = {ONE, ONE, ONE, ONE, ONE, ONE, ONE, ONE};
    accL = MFMA16(pf0, ones, accL);     // row-sum: free via matrix pipe
    accL = MFMA16(pf1, ones, accL);
    #pragma unroll
    for (int d = 0; d < 4; ++d) {
        const char* vb = (const char*)sVtc + (d * 16 + c) * 144;
        bf16x8 vf0 = *(const bf16x8*)(vb + g * 16);
        bf16x8 vf1 = *(const bf16x8*)(vb + 64 + g * 16);
        acc_o[d] = MFMA16(pf0, vf0, acc_o[d]);
        acc_o[d] = MFMA16(pf1, vf1, acc_o[d]);
    }
}

__global__ __launch_bounds__(256, 2)
void attn_kernel(const __hip_bfloat16* __restrict__ qkv,   // [B*L, 3072]
                 const float* __restrict__ alibi,          // [H, L, L]
                 const float* __restrict__ scales,         // [B]
                 __hip_bfloat16* __restrict__ out) {       // [B*L, 1024]
    __shared__ short sK[2][64 * 64];      // swizzled [64 kv][64 hd]
    __shared__ short sVt[2][64 * 72];     // [64 d][64 kv + 8 pad]
    __shared__ short sPA[4][16 * 72];
    __shared__ short sPB[4][16 * 72];

    const int p = blockIdx.x, h = blockIdx.y, b = blockIdx.z;
    const int qtA = p, qtB = 31 - p;
    const int nIter = qtB + 1;
    const int tid = threadIdx.x;
    const int wave = tid >> 6, lane = tid & 63;
    const int g = lane >> 4, c = lane & 15;
    const float scale = scales[b];
    const long base_bl = (long)b * 2048;

    const int qA0 = qtA * 64 + wave * 16;
    const int qB0 = qtB * 64 + wave * 16;

    const __hip_bfloat16* qrowA = qkv + (base_bl + qA0 + c) * 3072 + h * 64;
    const __hip_bfloat16* qrowB = qkv + (base_bl + qB0 + c) * 3072 + h * 64;
    bf16x8 qAf0 = *(const bf16x8*)(qrowA + g * 8);
    bf16x8 qAf1 = *(const bf16x8*)(qrowA + 32 + g * 8);
    bf16x8 qBf0 = *(const bf16x8*)(qrowB + g * 8);
    bf16x8 qBf1 = *(const bf16x8*)(qrowB + 32 + g * 8);

    const __hip_bfloat16* kg = qkv + base_bl * 3072 + 1024 + h * 64;
    const __hip_bfloat16* vg = qkv + base_bl * 3072 + 2048 + h * 64;
    const float* abA_base = alibi + (long)h * 2048 * 2048 + (long)(qA0 + g * 4) * 2048;
    const float* abB_base = alibi + (long)h * 2048 * 2048 + (long)(qB0 + g * 4) * 2048;

    // V transpose staging coords
    const int p2 = tid & 31;
    const int d0 = (tid >> 5) * 8;
    const __hip_bfloat16* vrow = vg + (long)(2 * p2) * 3072 + d0;

    f32x4 accA[4], accB[4], accLA, accLB;
    float mA[4], mB[4];
    #pragma unroll
    for (int d = 0; d < 4; ++d) {
        accA[d] = f32x4{0.f, 0.f, 0.f, 0.f};
        accB[d] = f32x4{0.f, 0.f, 0.f, 0.f};
    }
    accLA = f32x4{0.f, 0.f, 0.f, 0.f};
    accLB = f32x4{0.f, 0.f, 0.f, 0.f};
    #pragma unroll
    for (int r = 0; r < 4; ++r) { mA[r] = -3e38f; mB[r] = -3e38f; }

    float abA[4][4], abB[4][4], abAn[4][4], abBn[4][4];

    // prologue: stage tile 0 (K via gload_lds, V transpose via regs)
    {
        #pragma unroll
        for (int i = 0; i < 2; ++i) {
            int cb = (i * 4 + wave) * 64;
            int chunk = cb + lane;
            int row = chunk >> 3;
            int sc = ((chunk & 7) * 16) ^ ((row & 7) << 4);
            gload_lds16((const char*)(kg + (long)row * 3072) + sc,
                        (char*)sK[0] + cb * 16);
        }
        bf16x8 va = *(const bf16x8*)vrow;
        bf16x8 vb = *(const bf16x8*)(vrow + 3072);
        #pragma unroll
        for (int j = 0; j < 8; ++j) {
            unsigned pk = ((unsigned)(unsigned short)va[j]) |
                          (((unsigned)(unsigned short)vb[j]) << 16);
            *(unsigned*)((char*)sVt[0] + (d0 + j) * 144 + p2 * 4) = pk;
        }
        #pragma unroll
        for (int nf = 0; nf < 4; ++nf)
            #pragma unroll
            for (int r = 0; r < 4; ++r) {
                abA[nf][r] = abA_base[(long)r * 2048 + nf * 16 + c];
                abB[nf][r] = abB_base[(long)r * 2048 + nf * 16 + c];
                abAn[nf][r] = 0.f; abBn[nf][r] = 0.f;
            }
    }
    __syncthreads();

    for (int t = 0; t < nIter; ++t) {
        const int cur = t & 1;
        const int kv0 = t * 64;
        bf16x8 va, vb;
        const bool haveNext = (t + 1 < nIter);
        if (haveNext) {
            // issue next K tile (direct to LDS) + next V loads (to regs, write late)
            #pragma unroll
            for (int i = 0; i < 2; ++i) {
                int cb = (i * 4 + wave) * 64;
                int chunk = cb + lane;
                int row = chunk >> 3;
                int sc = ((chunk & 7) * 16) ^ ((row & 7) << 4);
                gload_lds16((const char*)(kg + (long)(kv0 + 64 + row) * 3072) + sc,
                            (char*)sK[cur ^ 1] + cb * 16);
            }
            const __hip_bfloat16* vp = vrow + (long)(kv0 + 64) * 3072;
            va = *(const bf16x8*)vp;
            vb = *(const bf16x8*)(vp + 3072);
            #pragma unroll
            for (int nf = 0; nf < 4; ++nf)
                #pragma unroll
                for (int r = 0; r < 4; ++r)
                    abBn[nf][r] = abB_base[(long)r * 2048 + kv0 + 64 + nf * 16 + c];
        }
        if (t + 1 <= qtA) {
            #pragma unroll
            for (int nf = 0; nf < 4; ++nf)
                #pragma unroll
                for (int r = 0; r < 4; ++r)
                    abAn[nf][r] = abA_base[(long)r * 2048 + kv0 + 64 + nf * 16 + c];
        }

        // hoisted K fragments (shared by both q-tiles)
        bf16x8 kf[4][2];
        const int swz = (c & 7) << 4;
        #pragma unroll
        for (int nf = 0; nf < 4; ++nf) {
            const char* kb = (const char*)sK[cur] + (nf * 16 + c) * 128;
            kf[nf][0] = *(const bf16x8*)(kb + ((g * 16) ^ swz));
            kf[nf][1] = *(const bf16x8*)(kb + ((64 + g * 16) ^ swz));
        }

        compute_tile(kf, sVt[cur], &sPB[wave][0], qBf0, qBf1,
                     accB, accLB, mB, abB, scale, qB0 + g * 4, kv0, t == qtB, g, c);
        if (t <= qtA)
            compute_tile(kf, sVt[cur], &sPA[wave][0], qAf0, qAf1,
                         accA, accLA, mA, abA, scale, qA0 + g * 4, kv0, t == qtA, g, c);

        if (haveNext) {
            #pragma unroll
            for (int j = 0; j < 8; ++j) {
                unsigned pk = ((unsigned)(unsigned short)va[j]) |
                              (((unsigned)(unsigned short)vb[j]) << 16);
                *(unsigned*)((char*)sVt[cur ^ 1] + (d0 + j) * 144 + p2 * 4) = pk;
            }
        }
        __syncthreads();
        #pragma unroll
        for (int nf = 0; nf < 4; ++nf)
            #pragma unroll
            for (int r = 0; r < 4; ++r) {
                abA[nf][r] = abAn[nf][r];
                abB[nf][r] = abBn[nf][r];
            }
    }

    __hip_bfloat16* opA = out + (base_bl + qA0 + g * 4) * 1024 + h * 64;
    __hip_bfloat16* opB = out + (base_bl + qB0 + g * 4) * 1024 + h * 64;
    #pragma unroll
    for (int r = 0; r < 4; ++r) {
        float invA = 1.0f / accLA[r];
        float invB = 1.0f / accLB[r];
        #pragma unroll
        for (int d = 0; d < 4; ++d) {
            opA[(long)r * 1024 + d * 16 + c] = __float2bfloat16(accA[d][r] * invA);
            opB[(long)r * 1024 + d * 16 + c] = __float2bfloat16(accB[d][r] * invB);
        }
    }
}

extern "C" void kernel_launch(void* const* d_in, const int* in_sizes, int n_in,
                              void* d_out, int out_size, void* d_ws, size_t ws_size,
                              hipStream_t stream) {
    const float* x      = (const float*)d_in[0];
    const float* phylo  = (const float*)d_in[1];
    const float* alibi  = (const float*)d_in[2];
    const float* qkv_w  = (const float*)d_in[4];
    const float* qkv_b  = (const float*)d_in[5];
    const float* out_w  = (const float*)d_in[6];
    const float* out_b  = (const float*)d_in[7];
    const float* alphap = (const float*)d_in[8];

    char* ws = (char*)d_ws;
    __hip_bfloat16* xbf   = (__hip_bfloat16*)(ws);                 // 8 MB
    __hip_bfloat16* qwbf  = (__hip_bfloat16*)(ws + (8l << 20));    // 6 MB
    __hip_bfloat16* owbf  = (__hip_bfloat16*)(ws + (14l << 20));   // 2 MB
    __hip_bfloat16* qkvbf = (__hip_bfloat16*)(ws + (16l << 20));   // 24 MB
    __hip_bfloat16* aobf  = (__hip_bfloat16*)(ws + (40l << 20));   // 8 MB
    float* scales         = (float*)(ws + (48l << 20));            // 2 floats

    prep_kernel<<<2050, 256, 0, stream>>>(x, qkv_w, out_w, phylo, alphap,
                                          (s4v*)xbf, (s4v*)qwbf, (s4v*)owbf, scales);

    gemm_nt<1, 4><<<dim3(24, 32), 256, 0, stream>>>(xbf, qwbf, qkv_b, qkvbf,
                                                    4096, 3072, 1024);
    attn_kernel<<<dim3(16, 16, 2), 256, 0, stream>>>(qkvbf, alibi, scales, aobf);
    gemm_nt<0, 2><<<dim3(16, 32), 256, 0, stream>>>(aobf, owbf, out_b, d_out,
                                                    4096, 1024, 1024);
}